// Round 5
// baseline (303.502 us; speedup 1.0000x reference)
//
#include <hip/hip_runtime.h>

// RelationMemory — Round 5: restore round-2 k_neg (proven 55.5us) + seq-2-group
// amortization; redesigned coalesced/swizzled k_projcopy; round-3 prep kernels.
//
// Algebra: linear(linear(x,Wm,bm),Wh,bh) == linear(x, Wh@Wm, Wh@bm+bh).
// MFMA: v_mfma_f32_16x16x32_bf16, fp32 via bf16 hi/lo split, 3 products
// (ah*bh + ah*bl + al*bh), rel err ~2^-17.
// Fragments: A row=lane&15, k=(lane>>4)*8+e; B col=lane&15; D row=(lane>>4)*4+r.

#define BB   128
#define DD   128
#define KK   16
#define NMEM 100000

static constexpr float INV_T = 1.0f / 0.07f;

// ws layout (float offsets)
#define WS_SE    0
#define WS_TE    16384
#define WS_MTV   32768
#define WS_MTQ   49152
#define WS_MSV   65536
#define WS_MSPQ  81920
#define WS_HT    98304            // 16384*128 floats -> ends 2195456
#define FR_TS_HI 2195456          // frag arrays: 16384 shorts = 8192 floats each
#define FR_TS_LO 2203648
#define FR_T_HI  2211840
#define FR_T_LO  2220032
#define FR_Q_HI  2228224
#define FR_Q_LO  2236416
#define BC_TS    2244608          // 128 floats
#define BC_T     2244736
#define WS_PROJ  2244864          // 100000*128 floats (51.2 MB)
#define OUT_MEM  278528           // memory_new offset in d_out

typedef __attribute__((ext_vector_type(8))) short short8v;
typedef __attribute__((ext_vector_type(4))) float f32x4;

// ---- cheap split: hi = bf16 half-up(x), lo = bf16 half-up(x - hi) ----
__device__ inline void split2(float x0, float x1, unsigned& hi, unsigned& lo) {
    unsigned u0 = __float_as_uint(x0), u1 = __float_as_uint(x1);
    unsigned h0 = (u0 + 0x8000u) & 0xffff0000u;
    unsigned h1 = (u1 + 0x8000u) & 0xffff0000u;
    float l0 = x0 - __uint_as_float(h0);
    float l1 = x1 - __uint_as_float(h1);
    unsigned v0 = __float_as_uint(l0) + 0x8000u;
    unsigned v1 = __float_as_uint(l1) + 0x8000u;
    hi = __builtin_amdgcn_perm(h1, h0, 0x07060302u);
    lo = __builtin_amdgcn_perm(v1, v0, 0x07060302u);
}

__device__ inline void split8(const float4& x0, const float4& x1, short8v& h8, short8v& l8) {
    uint4 H, L;
    split2(x0.x, x0.y, H.x, L.x);
    split2(x0.z, x0.w, H.y, L.y);
    split2(x1.x, x1.y, H.z, L.z);
    split2(x1.z, x1.w, H.w, L.w);
    h8 = *(short8v*)&H;
    l8 = *(short8v*)&L;
}

// ---------------------------------------------------------------- k_compose
// blocks 0..7:  Wc_ts = W_hts@W_mts (+bias)  -> FR_TS, BC_TS
// blocks 8..15: Wc_t  = W_ht @W_mt  (+bias)  -> FR_T,  BC_T
// block 16:     reorder/split W_tsq          -> FR_Q
__global__ __launch_bounds__(256) void k_compose(
    const float* __restrict__ W_mts, const float* __restrict__ b_mts,
    const float* __restrict__ W_hts, const float* __restrict__ b_hts,
    const float* __restrict__ W_mt,  const float* __restrict__ b_mt,
    const float* __restrict__ W_ht,  const float* __restrict__ b_ht,
    const float* __restrict__ W_tsq, float* __restrict__ ws)
{
    int bid = blockIdx.x;
    int tid = threadIdx.x;
    if (bid == 16) {
        short* FH = (short*)(ws + FR_Q_HI);
        short* FL = (short*)(ws + FR_Q_LO);
        int d = tid >> 1, k0 = (tid & 1) * 64;
        int t = d >> 4, col = d & 15;
        for (int kk = 0; kk < 64; kk += 8) {
            int k = k0 + kk;
            float4 x0 = *(const float4*)&W_tsq[d * 128 + k];
            float4 x1 = *(const float4*)&W_tsq[d * 128 + k + 4];
            short8v h8, l8; split8(x0, x1, h8, l8);
            int c = k >> 5, kg = (k >> 3) & 3;
            int a2 = (((t * 4 + c) * 4 + kg) * 16 + col) * 8;
            *(short8v*)&FH[a2] = h8;
            *(short8v*)&FL[a2] = l8;
        }
        return;
    }
    int which = bid >> 3;          // 0: ts, 1: t
    int sub = bid & 7;
    const float* A    = which ? W_ht : W_hts;
    const float* Bm   = which ? W_mt : W_mts;
    const float* bin  = which ? b_mt : b_mts;
    const float* bout = which ? b_ht : b_hts;
    short* FH = (short*)(ws + (which ? FR_T_HI : FR_TS_HI));
    short* FL = (short*)(ws + (which ? FR_T_LO : FR_TS_LO));
    float* BC = ws + (which ? BC_T : BC_TS);

    int d = sub * 16 + (tid >> 4);
    int k0 = (tid & 15) * 8;
    float a8[8];
    #pragma unroll
    for (int q = 0; q < 8; ++q) a8[q] = 0.f;
    for (int m = 0; m < 128; ++m) {
        float a = A[d * 128 + m];
        float4 b0 = *(const float4*)&Bm[m * 128 + k0];
        float4 b1 = *(const float4*)&Bm[m * 128 + k0 + 4];
        a8[0] = fmaf(a, b0.x, a8[0]); a8[1] = fmaf(a, b0.y, a8[1]);
        a8[2] = fmaf(a, b0.z, a8[2]); a8[3] = fmaf(a, b0.w, a8[3]);
        a8[4] = fmaf(a, b1.x, a8[4]); a8[5] = fmaf(a, b1.y, a8[5]);
        a8[6] = fmaf(a, b1.z, a8[6]); a8[7] = fmaf(a, b1.w, a8[7]);
    }
    float4 x0 = make_float4(a8[0], a8[1], a8[2], a8[3]);
    float4 x1 = make_float4(a8[4], a8[5], a8[6], a8[7]);
    short8v h8, l8; split8(x0, x1, h8, l8);
    int t = d >> 4, col = d & 15, c = k0 >> 5, kg = (k0 >> 3) & 3;
    int a2 = (((t * 4 + c) * 4 + kg) * 16 + col) * 8;
    *(short8v*)&FH[a2] = h8;
    *(short8v*)&FL[a2] = l8;

    if (sub == 0 && tid < 128) {
        float a = bout[tid];
        for (int m = 0; m < 128; ++m) a = fmaf(A[tid * 128 + m], bin[m], a);
        BC[tid] = a;
    }
}

// ---------------------------------------------------------------- k_embed
__global__ __launch_bounds__(128) void k_embed(
    const float* __restrict__ s, const float* __restrict__ t,
    const float* __restrict__ W_es, const float* __restrict__ b_es,
    const float* __restrict__ W_et, const float* __restrict__ b_et,
    float* __restrict__ ws)
{
    __shared__ float xs[1024];
    int bid = blockIdx.x;
    int which = bid >> 7;
    int r = bid & 127;
    const float* x    = which ? (t + (long)r * 1024) : (s + (long)r * 1024);
    const float* W    = which ? W_et : W_es;
    const float* bias = which ? b_et : b_es;
    float* outp = ws + (which ? WS_TE : WS_SE) + r * DD;

    int tid = threadIdx.x;
    for (int i = tid; i < 1024; i += 128) xs[i] = x[i];
    __syncthreads();

    const float* Wr = W + (long)tid * 1024;
    float a0 = 0.f, a1 = 0.f, a2 = 0.f, a3 = 0.f;
    #pragma unroll 4
    for (int k = 0; k < 1024; k += 16) {
        float4 xv0 = *(const float4*)&xs[k],      wv0 = *(const float4*)&Wr[k];
        float4 xv1 = *(const float4*)&xs[k + 4],  wv1 = *(const float4*)&Wr[k + 4];
        float4 xv2 = *(const float4*)&xs[k + 8],  wv2 = *(const float4*)&Wr[k + 8];
        float4 xv3 = *(const float4*)&xs[k + 12], wv3 = *(const float4*)&Wr[k + 12];
        a0 = fmaf(xv0.x, wv0.x, fmaf(xv0.y, wv0.y, fmaf(xv0.z, wv0.z, fmaf(xv0.w, wv0.w, a0))));
        a1 = fmaf(xv1.x, wv1.x, fmaf(xv1.y, wv1.y, fmaf(xv1.z, wv1.z, fmaf(xv1.w, wv1.w, a1))));
        a2 = fmaf(xv2.x, wv2.x, fmaf(xv2.y, wv2.y, fmaf(xv2.z, wv2.z, fmaf(xv2.w, wv2.w, a2))));
        a3 = fmaf(xv3.x, wv3.x, fmaf(xv3.y, wv3.y, fmaf(xv3.z, wv3.z, fmaf(xv3.w, wv3.w, a3))));
    }
    outp[tid] = bias[tid] + ((a0 + a1) + (a2 + a3));
}

// ---------------------------------------------------------------- k_proj4
__global__ __launch_bounds__(128) void k_proj4(
    const float* __restrict__ W_tv,  const float* __restrict__ b_tv,
    const float* __restrict__ W_tq,  const float* __restrict__ b_tq,
    const float* __restrict__ W_tsv, const float* __restrict__ b_tsv,
    const float* __restrict__ W_tsq, const float* __restrict__ b_tsq,
    float* __restrict__ ws)
{
    int bid = blockIdx.x;
    int which = bid >> 7;
    int r = bid & 127;
    const float *W, *bias, *in;
    float* outp;
    switch (which) {
        case 0:  W = W_tv;  bias = b_tv;  in = ws + WS_TE; outp = ws + WS_MTV;  break;
        case 1:  W = W_tq;  bias = b_tq;  in = ws + WS_TE; outp = ws + WS_MTQ;  break;
        case 2:  W = W_tsv; bias = b_tsv; in = ws + WS_TE; outp = ws + WS_MSV;  break;
        default: W = W_tsq; bias = b_tsq; in = ws + WS_SE; outp = ws + WS_MSPQ; break;
    }
    int d = threadIdx.x;
    const float* xr = in + r * DD;
    const float* Wr = W + d * DD;
    float a0 = 0.f, a1 = 0.f, a2 = 0.f, a3 = 0.f;
    #pragma unroll
    for (int k = 0; k < DD; k += 16) {
        float4 xv0 = *(const float4*)&xr[k],      wv0 = *(const float4*)&Wr[k];
        float4 xv1 = *(const float4*)&xr[k + 4],  wv1 = *(const float4*)&Wr[k + 4];
        float4 xv2 = *(const float4*)&xr[k + 8],  wv2 = *(const float4*)&Wr[k + 8];
        float4 xv3 = *(const float4*)&xr[k + 12], wv3 = *(const float4*)&Wr[k + 12];
        a0 = fmaf(xv0.x, wv0.x, fmaf(xv0.y, wv0.y, fmaf(xv0.z, wv0.z, fmaf(xv0.w, wv0.w, a0))));
        a1 = fmaf(xv1.x, wv1.x, fmaf(xv1.y, wv1.y, fmaf(xv1.z, wv1.z, fmaf(xv1.w, wv1.w, a1))));
        a2 = fmaf(xv2.x, wv2.x, fmaf(xv2.y, wv2.y, fmaf(xv2.z, wv2.z, fmaf(xv2.w, wv2.w, a2))));
        a3 = fmaf(xv3.x, wv3.x, fmaf(xv3.y, wv3.y, fmaf(xv3.z, wv3.z, fmaf(xv3.w, wv3.w, a3))));
    }
    outp[r * DD + d] = bias[d] + ((a0 + a1) + (a2 + a3));
}

// ---------------------------------------------------------------- k_projcopy
// Coalesced redesign: block = 512 thr / 8 waves; stage 128 rows (64KB) of mem
// into XOR-swizzled LDS with perfect 1KB/instr loads; each wave owns 16 rows:
// copy-out (coalesced), A-fragment reads (swizzle => <=2-way banks), MFMA,
// acc bounce into own LDS region, coalesced proj store. 782 blocks.
__global__ __launch_bounds__(512, 1) void k_projcopy(
    const float* __restrict__ mem, const float* __restrict__ b_tsq,
    const float* __restrict__ ws, float* __restrict__ proj, float* __restrict__ dst)
{
    __shared__ short Bh[16384], Bl[16384];   // 64 KB  B fragments
    __shared__ float As[16384];              // 64 KB  A stage (128 rows x 512B)
    int tid = threadIdx.x;

    const short* frh = (const short*)(ws + FR_Q_HI);
    const short* frl = (const short*)(ws + FR_Q_LO);
    for (int i2 = tid; i2 < 2048; i2 += 512) {
        ((uint4*)Bh)[i2] = ((const uint4*)frh)[i2];
        ((uint4*)Bl)[i2] = ((const uint4*)frl)[i2];
    }

    long row0 = (long)blockIdx.x * 128;
    {
        const char* gb = (const char*)mem;
        char* lb = (char*)As;
        #pragma unroll
        for (int q = 0; q < 8; ++q) {
            int L = q * 8192 + tid * 16;
            int lrow = L >> 9;
            long grow = row0 + lrow;
            if (grow > NMEM - 1) grow = NMEM - 1;
            float4 v = *(const float4*)(gb + grow * 512 + (L & 511));
            *(float4*)(lb + (L ^ ((lrow & 7) << 4))) = v;
        }
    }
    __syncthreads();

    int lane = tid & 63, w = tid >> 6;
    int col = lane & 15, rq = lane >> 4;
    const char* lb = (const char*)As;

    // ---- copy-out: wave-private 8KB, coalesced 1KB stores ----
    {
        char* db = (char*)dst;
        #pragma unroll
        for (int q = 0; q < 8; ++q) {
            int L = w * 8192 + q * 1024 + lane * 16;
            int lrow = L >> 9;
            float4 v = *(const float4*)(lb + (L ^ ((lrow & 7) << 4)));
            long grow = row0 + lrow;
            if (grow < NMEM) *(float4*)(db + grow * 512 + (L & 511)) = v;
        }
    }

    // ---- A fragments from swizzled LDS ----
    int R = w * 16 + col;
    short8v ah[4], al[4];
    #pragma unroll
    for (int c = 0; c < 4; ++c) {
        int off = c * 128 + rq * 32;
        int sw = (R & 7) << 4;
        float4 x0 = *(const float4*)(lb + R * 512 + (off ^ sw));
        float4 x1 = *(const float4*)(lb + R * 512 + ((off + 16) ^ sw));
        split8(x0, x1, ah[c], al[c]);
    }

    // ---- MFMA + bounce acc into own region (overwrites consumed A) ----
    char* lw = (char*)As;
    #pragma unroll
    for (int t = 0; t < 8; ++t) {
        float b0 = b_tsq[t * 16 + col];
        f32x4 a; a[0] = b0; a[1] = b0; a[2] = b0; a[3] = b0;
        #pragma unroll
        for (int c = 0; c < 4; ++c) {
            int off = ((t * 4 + c) * 64 + lane) * 8;
            short8v bh = *(const short8v*)&Bh[off];
            short8v bl = *(const short8v*)&Bl[off];
            a = __builtin_amdgcn_mfma_f32_16x16x32_bf16(al[c], bh, a, 0, 0, 0);
            a = __builtin_amdgcn_mfma_f32_16x16x32_bf16(ah[c], bl, a, 0, 0, 0);
            a = __builtin_amdgcn_mfma_f32_16x16x32_bf16(ah[c], bh, a, 0, 0, 0);
        }
        #pragma unroll
        for (int r = 0; r < 4; ++r) {
            int lrow = rq * 4 + r;
            int L = (w * 16 + lrow) * 512 + (t * 16 + col) * 4;
            *(float*)(lw + (L ^ ((lrow & 7) << 4))) = a[r];
        }
    }

    // ---- proj out: wave-private 8KB, coalesced 1KB stores ----
    {
        char* pb = (char*)proj;
        #pragma unroll
        for (int q = 0; q < 8; ++q) {
            int L = w * 8192 + q * 1024 + lane * 16;
            int lrow = L >> 9;
            float4 v = *(const float4*)(lb + (L ^ ((lrow & 7) << 4)));
            long grow = row0 + lrow;
            if (grow < NMEM) *(float4*)(pb + grow * 512 + (L & 511)) = v;
        }
    }
}

// ---------------------------------------------------------------- k_ht_mfma
__global__ __launch_bounds__(512, 2) void k_ht_mfma(float* __restrict__ ws)
{
    __shared__ short Bh[16384], Bl[16384];
    const short* frh = (const short*)(ws + FR_T_HI);
    const short* frl = (const short*)(ws + FR_T_LO);
    int tid = threadIdx.x;
    for (int i2 = tid; i2 < 2048; i2 += 512) {
        ((uint4*)Bh)[i2] = ((const uint4*)frh)[i2];
        ((uint4*)Bl)[i2] = ((const uint4*)frl)[i2];
    }
    __syncthreads();

    const float* mtv = ws + WS_MTV;
    const float* mtq = ws + WS_MTQ;
    const float* bc  = ws + BC_T;
    float* ht = ws + WS_HT;

    int lane = tid & 63, w = tid >> 6;
    int col = lane & 15, rq = lane >> 4;
    int g = blockIdx.x * 8 + w;
    int p = g * 16 + col;
    int i = p >> 7, j = p & 127;
    int kg = rq * 8;
    const float* vj = mtv + j * 128;
    const float* qi = mtq + i * 128;

    short8v ah[4], al[4];
    #pragma unroll
    for (int c = 0; c < 4; ++c) {
        int ko = c * 32 + kg;
        float4 v0 = *(const float4*)&vj[ko], v1 = *(const float4*)&vj[ko + 4];
        float4 q0 = *(const float4*)&qi[ko], q1 = *(const float4*)&qi[ko + 4];
        float4 r0 = make_float4(fmaxf(v0.x - q0.x, 0.f), fmaxf(v0.y - q0.y, 0.f),
                                fmaxf(v0.z - q0.z, 0.f), fmaxf(v0.w - q0.w, 0.f));
        float4 r1 = make_float4(fmaxf(v1.x - q1.x, 0.f), fmaxf(v1.y - q1.y, 0.f),
                                fmaxf(v1.z - q1.z, 0.f), fmaxf(v1.w - q1.w, 0.f));
        split8(r0, r1, ah[c], al[c]);
    }

    f32x4 acc[8];
    #pragma unroll
    for (int t = 0; t < 8; ++t) {
        float b0 = bc[t * 16 + col];
        f32x4 a; a[0] = b0; a[1] = b0; a[2] = b0; a[3] = b0;
        #pragma unroll
        for (int c = 0; c < 4; ++c) {
            int off = ((t * 4 + c) * 64 + lane) * 8;
            short8v bh = *(const short8v*)&Bh[off];
            short8v bl = *(const short8v*)&Bl[off];
            a = __builtin_amdgcn_mfma_f32_16x16x32_bf16(al[c], bh, a, 0, 0, 0);
            a = __builtin_amdgcn_mfma_f32_16x16x32_bf16(ah[c], bl, a, 0, 0, 0);
            a = __builtin_amdgcn_mfma_f32_16x16x32_bf16(ah[c], bh, a, 0, 0, 0);
        }
        acc[t] = a;
    }

    #pragma unroll
    for (int r = 0; r < 4; ++r) {
        long rho = g * 16 + rq * 4 + r;
        float s_uu = 0.f;
        #pragma unroll
        for (int t = 0; t < 8; ++t) { float u = acc[t][r]; s_uu = fmaf(u, u, s_uu); }
        #pragma unroll
        for (int m = 1; m < 16; m <<= 1) s_uu += __shfl_xor(s_uu, m);
        float rn = rsqrtf(s_uu);
        #pragma unroll
        for (int t = 0; t < 8; ++t)
            ht[rho * 128 + t * 16 + col] = acc[t][r] * rn;
    }
}

// ---------------------------------------------------------------- k_neg_mfma
// 278528 rows = 17408 groups of 16; 1088 blocks x 8 waves x 2 sequential
// groups per wave (amortizes the 64KB B staging). Round-2-proven body.
__global__ __launch_bounds__(512, 2) void k_neg_mfma(
    const float* __restrict__ ws, const int* __restrict__ idx,
    const float* __restrict__ proj, float* __restrict__ out)
{
    __shared__ short Bh[16384], Bl[16384];
    const short* frh = (const short*)(ws + FR_TS_HI);
    const short* frl = (const short*)(ws + FR_TS_LO);
    int tid = threadIdx.x;
    for (int i2 = tid; i2 < 2048; i2 += 512) {
        ((uint4*)Bh)[i2] = ((const uint4*)frh)[i2];
        ((uint4*)Bl)[i2] = ((const uint4*)frl)[i2];
    }
    __syncthreads();

    const float* msv  = ws + WS_MSV;
    const float* mspq = ws + WS_MSPQ;
    const float* ht   = ws + WS_HT;
    const float* bc   = ws + BC_TS;

    int lane = tid & 63, w = tid >> 6;
    int col = lane & 15, rq = lane >> 4;
    int kg = rq * 8;

    for (int it = 0; it < 2; ++it) {
        int g = blockIdx.x * 16 + it * 8 + w;

        int rowA = g * 16 + col;
        int p = rowA / 17;
        int slot = rowA - p * 17;
        const float* src = slot ? (proj + (long)idx[p * 17 + slot - 1] * 128)
                                : (mspq + (p >> 7) * 128);
        const float* vj = msv + (p & 127) * 128;

        short8v ah[4], al[4];
        #pragma unroll
        for (int c = 0; c < 4; ++c) {
            int ko = c * 32 + kg;
            float4 v0 = *(const float4*)&vj[ko],  v1 = *(const float4*)&vj[ko + 4];
            float4 q0 = *(const float4*)&src[ko], q1 = *(const float4*)&src[ko + 4];
            float4 r0 = make_float4(fmaxf(v0.x - q0.x, 0.f), fmaxf(v0.y - q0.y, 0.f),
                                    fmaxf(v0.z - q0.z, 0.f), fmaxf(v0.w - q0.w, 0.f));
            float4 r1 = make_float4(fmaxf(v1.x - q1.x, 0.f), fmaxf(v1.y - q1.y, 0.f),
                                    fmaxf(v1.z - q1.z, 0.f), fmaxf(v1.w - q1.w, 0.f));
            split8(r0, r1, ah[c], al[c]);
        }

        f32x4 acc[8];
        #pragma unroll
        for (int t = 0; t < 8; ++t) {
            float b0 = bc[t * 16 + col];
            f32x4 a; a[0] = b0; a[1] = b0; a[2] = b0; a[3] = b0;
            #pragma unroll
            for (int c = 0; c < 4; ++c) {
                int off = ((t * 4 + c) * 64 + lane) * 8;
                short8v bh = *(const short8v*)&Bh[off];
                short8v bl = *(const short8v*)&Bl[off];
                a = __builtin_amdgcn_mfma_f32_16x16x32_bf16(al[c], bh, a, 0, 0, 0);
                a = __builtin_amdgcn_mfma_f32_16x16x32_bf16(ah[c], bl, a, 0, 0, 0);
                a = __builtin_amdgcn_mfma_f32_16x16x32_bf16(ah[c], bh, a, 0, 0, 0);
            }
            acc[t] = a;
        }

        #pragma unroll
        for (int r = 0; r < 4; ++r) {
            int rho = g * 16 + rq * 4 + r;
            int pe = rho / 17;
            const float* hrow = ht + (long)pe * 128 + col;
            float s_uu = 0.f, s_hu = 0.f;
            #pragma unroll
            for (int t = 0; t < 8; ++t) {
                float u = acc[t][r];
                s_uu = fmaf(u, u, s_uu);
                s_hu = fmaf(hrow[t * 16], u, s_hu);
            }
            #pragma unroll
            for (int m = 1; m < 16; m <<= 1) {
                s_uu += __shfl_xor(s_uu, m);
                s_hu += __shfl_xor(s_hu, m);
            }
            if (col == 0)
                out[rho] = __expf((s_hu * rsqrtf(s_uu) - 1.0f) * INV_T);
        }
    }
}

// ---------------------------------------------------------------- k_memupd
__global__ __launch_bounds__(128) void k_memupd(
    const float* __restrict__ mem, const float* __restrict__ se,
    const int* __restrict__ y, float* __restrict__ dst)
{
    int b = blockIdx.x;
    int d = threadIdx.x;
    int yb = y[b];
    for (int b2 = b + 1; b2 < BB; ++b2)
        if (y[b2] == yb) return;

    float ab = 0.5f * mem[(long)yb * 128 + d] + 0.5f * se[b * 128 + d];
    float ss = ab * ab;
    #pragma unroll
    for (int mq = 32; mq; mq >>= 1) ss += __shfl_xor(ss, mq);
    __shared__ float partial[2];
    if ((d & 63) == 0) partial[d >> 6] = ss;
    __syncthreads();
    float tot = partial[0] + partial[1];
    dst[(long)yb * 128 + d] = ab * rsqrtf(tot);
}

// ---------------------------------------------------------------- launch
extern "C" void kernel_launch(void* const* d_in, const int* in_sizes, int n_in,
                              void* d_out, int out_size, void* d_ws, size_t ws_size,
                              hipStream_t stream)
{
    const float* s     = (const float*)d_in[0];
    const float* t     = (const float*)d_in[1];
    const int*   y     = (const int*)  d_in[2];
    const int*   idx   = (const int*)  d_in[3];
    const float* mem   = (const float*)d_in[4];
    const float* W_es  = (const float*)d_in[5];  const float* b_es  = (const float*)d_in[6];
    const float* W_et  = (const float*)d_in[7];  const float* b_et  = (const float*)d_in[8];
    const float* W_tv  = (const float*)d_in[9];  const float* b_tv  = (const float*)d_in[10];
    const float* W_tq  = (const float*)d_in[11]; const float* b_tq  = (const float*)d_in[12];
    const float* W_tsv = (const float*)d_in[13]; const float* b_tsv = (const float*)d_in[14];
    const float* W_tsq = (const float*)d_in[15]; const float* b_tsq = (const float*)d_in[16];
    const float* W_mt  = (const float*)d_in[17]; const float* b_mt  = (const float*)d_in[18];
    const float* W_mts = (const float*)d_in[19]; const float* b_mts = (const float*)d_in[20];
    const float* W_ht  = (const float*)d_in[21]; const float* b_ht  = (const float*)d_in[22];
    const float* W_hts = (const float*)d_in[23]; const float* b_hts = (const float*)d_in[24];

    float* out  = (float*)d_out;
    float* ws   = (float*)d_ws;
    float* proj = ws + WS_PROJ;

    k_compose <<<17, 256, 0, stream>>>(W_mts, b_mts, W_hts, b_hts,
                                       W_mt, b_mt, W_ht, b_ht, W_tsq, ws);
    k_embed   <<<256, 128, 0, stream>>>(s, t, W_es, b_es, W_et, b_et, ws);
    k_projcopy<<<782, 512, 0, stream>>>(mem, b_tsq, ws, proj, out + OUT_MEM);
    k_proj4   <<<512, 128, 0, stream>>>(W_tv, b_tv, W_tq, b_tq, W_tsv, b_tsv, W_tsq, b_tsq, ws);
    k_ht_mfma <<<128, 512, 0, stream>>>(ws);
    k_neg_mfma<<<1088, 512, 0, stream>>>(ws, idx, proj, out);
    k_memupd  <<<128, 128, 0, stream>>>(mem, ws + WS_SE, y, out + OUT_MEM);
}

// Round 6
// 154.893 us; speedup vs baseline: 1.9594x; 1.9594x over previous
//
#include <hip/hip_runtime.h>

// RelationMemory — Round 6: k_neg restored EXACTLY to round-2 (55.5us proven,
// VGPR 52, one 16-row group per wave, grid 2176 — rounds 3/5 proved any
// multi-group-per-wave variant spills acc to scratch). New two-phase
// k_projcopy: linear copy warms L2, then L2-hot fragment gather + MFMA.
//
// Algebra: linear(linear(x,Wm,bm),Wh,bh) == linear(x, Wh@Wm, Wh@bm+bh).
// MFMA: v_mfma_f32_16x16x32_bf16, fp32 via bf16 hi/lo split, 3 products
// (ah*bh + ah*bl + al*bh), rel err ~2^-17.
// Fragments: A row=lane&15, k=(lane>>4)*8+e; B col=lane&15; D row=(lane>>4)*4+r.

#define BB   128
#define DD   128
#define KK   16
#define NMEM 100000

static constexpr float INV_T = 1.0f / 0.07f;

// ws layout (float offsets)
#define WS_SE    0
#define WS_TE    16384
#define WS_MTV   32768
#define WS_MTQ   49152
#define WS_MSV   65536
#define WS_MSPQ  81920
#define WS_HT    98304            // 16384*128 floats -> ends 2195456
#define FR_TS_HI 2195456          // frag arrays: 16384 shorts = 8192 floats each
#define FR_TS_LO 2203648
#define FR_T_HI  2211840
#define FR_T_LO  2220032
#define BC_TS    2244608          // 128 floats
#define BC_T     2244736
#define WS_PROJ  2244864          // 100000*128 floats (51.2 MB)
#define OUT_MEM  278528           // memory_new offset in d_out

typedef __attribute__((ext_vector_type(8))) short short8v;
typedef __attribute__((ext_vector_type(4))) float f32x4;

// ---- cheap split: hi = bf16 half-up(x), lo = bf16 half-up(x - hi) ----
__device__ inline void split2(float x0, float x1, unsigned& hi, unsigned& lo) {
    unsigned u0 = __float_as_uint(x0), u1 = __float_as_uint(x1);
    unsigned h0 = (u0 + 0x8000u) & 0xffff0000u;
    unsigned h1 = (u1 + 0x8000u) & 0xffff0000u;
    float l0 = x0 - __uint_as_float(h0);
    float l1 = x1 - __uint_as_float(h1);
    unsigned v0 = __float_as_uint(l0) + 0x8000u;
    unsigned v1 = __float_as_uint(l1) + 0x8000u;
    hi = __builtin_amdgcn_perm(h1, h0, 0x07060302u);
    lo = __builtin_amdgcn_perm(v1, v0, 0x07060302u);
}

__device__ inline void split8(const float4& x0, const float4& x1, short8v& h8, short8v& l8) {
    uint4 H, L;
    split2(x0.x, x0.y, H.x, L.x);
    split2(x0.z, x0.w, H.y, L.y);
    split2(x1.x, x1.y, H.z, L.z);
    split2(x1.z, x1.w, H.w, L.w);
    h8 = *(short8v*)&H;
    l8 = *(short8v*)&L;
}

// ---------------------------------------------------------------- k_compose
// blocks 0..7:  Wc_ts = W_hts@W_mts (+bias)  -> FR_TS, BC_TS
// blocks 8..15: Wc_t  = W_ht @W_mt  (+bias)  -> FR_T,  BC_T
__global__ __launch_bounds__(256) void k_compose(
    const float* __restrict__ W_mts, const float* __restrict__ b_mts,
    const float* __restrict__ W_hts, const float* __restrict__ b_hts,
    const float* __restrict__ W_mt,  const float* __restrict__ b_mt,
    const float* __restrict__ W_ht,  const float* __restrict__ b_ht,
    float* __restrict__ ws)
{
    int bid = blockIdx.x;
    int tid = threadIdx.x;
    int which = bid >> 3;          // 0: ts, 1: t
    int sub = bid & 7;
    const float* A    = which ? W_ht : W_hts;
    const float* Bm   = which ? W_mt : W_mts;
    const float* bin  = which ? b_mt : b_mts;
    const float* bout = which ? b_ht : b_hts;
    short* FH = (short*)(ws + (which ? FR_T_HI : FR_TS_HI));
    short* FL = (short*)(ws + (which ? FR_T_LO : FR_TS_LO));
    float* BC = ws + (which ? BC_T : BC_TS);

    int d = sub * 16 + (tid >> 4);
    int k0 = (tid & 15) * 8;
    float a8[8];
    #pragma unroll
    for (int q = 0; q < 8; ++q) a8[q] = 0.f;
    for (int m = 0; m < 128; ++m) {
        float a = A[d * 128 + m];
        float4 b0 = *(const float4*)&Bm[m * 128 + k0];
        float4 b1 = *(const float4*)&Bm[m * 128 + k0 + 4];
        a8[0] = fmaf(a, b0.x, a8[0]); a8[1] = fmaf(a, b0.y, a8[1]);
        a8[2] = fmaf(a, b0.z, a8[2]); a8[3] = fmaf(a, b0.w, a8[3]);
        a8[4] = fmaf(a, b1.x, a8[4]); a8[5] = fmaf(a, b1.y, a8[5]);
        a8[6] = fmaf(a, b1.z, a8[6]); a8[7] = fmaf(a, b1.w, a8[7]);
    }
    float4 x0 = make_float4(a8[0], a8[1], a8[2], a8[3]);
    float4 x1 = make_float4(a8[4], a8[5], a8[6], a8[7]);
    short8v h8, l8; split8(x0, x1, h8, l8);
    int t = d >> 4, col = d & 15, c = k0 >> 5, kg = (k0 >> 3) & 3;
    int a2 = (((t * 4 + c) * 4 + kg) * 16 + col) * 8;
    *(short8v*)&FH[a2] = h8;
    *(short8v*)&FL[a2] = l8;

    if (sub == 0 && tid < 128) {
        float a = bout[tid];
        for (int m = 0; m < 128; ++m) a = fmaf(A[tid * 128 + m], bin[m], a);
        BC[tid] = a;
    }
}

// ---------------------------------------------------------------- k_embed
__global__ __launch_bounds__(128) void k_embed(
    const float* __restrict__ s, const float* __restrict__ t,
    const float* __restrict__ W_es, const float* __restrict__ b_es,
    const float* __restrict__ W_et, const float* __restrict__ b_et,
    float* __restrict__ ws)
{
    __shared__ float xs[1024];
    int bid = blockIdx.x;
    int which = bid >> 7;
    int r = bid & 127;
    const float* x    = which ? (t + (long)r * 1024) : (s + (long)r * 1024);
    const float* W    = which ? W_et : W_es;
    const float* bias = which ? b_et : b_es;
    float* outp = ws + (which ? WS_TE : WS_SE) + r * DD;

    int tid = threadIdx.x;
    for (int i = tid; i < 1024; i += 128) xs[i] = x[i];
    __syncthreads();

    const float* Wr = W + (long)tid * 1024;
    float a0 = 0.f, a1 = 0.f, a2 = 0.f, a3 = 0.f;
    #pragma unroll 4
    for (int k = 0; k < 1024; k += 16) {
        float4 xv0 = *(const float4*)&xs[k],      wv0 = *(const float4*)&Wr[k];
        float4 xv1 = *(const float4*)&xs[k + 4],  wv1 = *(const float4*)&Wr[k + 4];
        float4 xv2 = *(const float4*)&xs[k + 8],  wv2 = *(const float4*)&Wr[k + 8];
        float4 xv3 = *(const float4*)&xs[k + 12], wv3 = *(const float4*)&Wr[k + 12];
        a0 = fmaf(xv0.x, wv0.x, fmaf(xv0.y, wv0.y, fmaf(xv0.z, wv0.z, fmaf(xv0.w, wv0.w, a0))));
        a1 = fmaf(xv1.x, wv1.x, fmaf(xv1.y, wv1.y, fmaf(xv1.z, wv1.z, fmaf(xv1.w, wv1.w, a1))));
        a2 = fmaf(xv2.x, wv2.x, fmaf(xv2.y, wv2.y, fmaf(xv2.z, wv2.z, fmaf(xv2.w, wv2.w, a2))));
        a3 = fmaf(xv3.x, wv3.x, fmaf(xv3.y, wv3.y, fmaf(xv3.z, wv3.z, fmaf(xv3.w, wv3.w, a3))));
    }
    outp[tid] = bias[tid] + ((a0 + a1) + (a2 + a3));
}

// ---------------------------------------------------------------- k_proj4
__global__ __launch_bounds__(128) void k_proj4(
    const float* __restrict__ W_tv,  const float* __restrict__ b_tv,
    const float* __restrict__ W_tq,  const float* __restrict__ b_tq,
    const float* __restrict__ W_tsv, const float* __restrict__ b_tsv,
    const float* __restrict__ W_tsq, const float* __restrict__ b_tsq,
    float* __restrict__ ws)
{
    int bid = blockIdx.x;
    int which = bid >> 7;
    int r = bid & 127;
    const float *W, *bias, *in;
    float* outp;
    switch (which) {
        case 0:  W = W_tv;  bias = b_tv;  in = ws + WS_TE; outp = ws + WS_MTV;  break;
        case 1:  W = W_tq;  bias = b_tq;  in = ws + WS_TE; outp = ws + WS_MTQ;  break;
        case 2:  W = W_tsv; bias = b_tsv; in = ws + WS_TE; outp = ws + WS_MSV;  break;
        default: W = W_tsq; bias = b_tsq; in = ws + WS_SE; outp = ws + WS_MSPQ; break;
    }
    int d = threadIdx.x;
    const float* xr = in + r * DD;
    const float* Wr = W + d * DD;
    float a0 = 0.f, a1 = 0.f, a2 = 0.f, a3 = 0.f;
    #pragma unroll
    for (int k = 0; k < DD; k += 16) {
        float4 xv0 = *(const float4*)&xr[k],      wv0 = *(const float4*)&Wr[k];
        float4 xv1 = *(const float4*)&xr[k + 4],  wv1 = *(const float4*)&Wr[k + 4];
        float4 xv2 = *(const float4*)&xr[k + 8],  wv2 = *(const float4*)&Wr[k + 8];
        float4 xv3 = *(const float4*)&xr[k + 12], wv3 = *(const float4*)&Wr[k + 12];
        a0 = fmaf(xv0.x, wv0.x, fmaf(xv0.y, wv0.y, fmaf(xv0.z, wv0.z, fmaf(xv0.w, wv0.w, a0))));
        a1 = fmaf(xv1.x, wv1.x, fmaf(xv1.y, wv1.y, fmaf(xv1.z, wv1.z, fmaf(xv1.w, wv1.w, a1))));
        a2 = fmaf(xv2.x, wv2.x, fmaf(xv2.y, wv2.y, fmaf(xv2.z, wv2.z, fmaf(xv2.w, wv2.w, a2))));
        a3 = fmaf(xv3.x, wv3.x, fmaf(xv3.y, wv3.y, fmaf(xv3.z, wv3.z, fmaf(xv3.w, wv3.w, a3))));
    }
    outp[r * DD + d] = bias[d] + ((a0 + a1) + (a2 + a3));
}

// ---------------------------------------------------------------- k_projcopy
// Two-phase: (1) fully-coalesced copy of this block's 128 rows (64KB) mem->dst,
// which also warms L2; (2) fragment loads of the same rows (L2-hot), MFMA,
// proj store. Self-splits W_tsq into LDS (no compose dependency). 782 blocks.
__global__ __launch_bounds__(512, 2) void k_projcopy(
    const float* __restrict__ mem, const float* __restrict__ b_tsq,
    const float* __restrict__ W_tsq,
    float* __restrict__ proj, float* __restrict__ dst)
{
    __shared__ short Bh[16384], Bl[16384];
    int tid = threadIdx.x;

    // ---- self-split W_tsq into LDS B-fragments (32 elems/thread) ----
    {
        int d = tid >> 2, k0 = (tid & 3) * 32;
        int tt = d >> 4, col = d & 15;
        #pragma unroll
        for (int h = 0; h < 4; ++h) {
            int k = k0 + h * 8;
            float4 x0 = *(const float4*)&W_tsq[d * 128 + k];
            float4 x1 = *(const float4*)&W_tsq[d * 128 + k + 4];
            short8v h8, l8; split8(x0, x1, h8, l8);
            int c = k >> 5, kg = (k >> 3) & 3;
            int a2 = (((tt * 4 + c) * 4 + kg) * 16 + col) * 8;
            *(short8v*)&Bh[a2] = h8;
            *(short8v*)&Bl[a2] = l8;
        }
    }

    // ---- phase 1: linear copy, 512 thr x 16B x 8 iters = 64KB ----
    long base = (long)blockIdx.x * 16384;       // float index of row block start
    #pragma unroll
    for (int q = 0; q < 8; ++q) {
        long fidx = base + q * 2048 + tid * 4;
        if (fidx < (long)NMEM * 128) {
            float4 v = *(const float4*)&mem[fidx];
            *(float4*)&dst[fidx] = v;
        }
    }
    __syncthreads();

    // ---- phase 2: one 16-row group per wave (8 groups = 128 rows) ----
    int lane = tid & 63, w = tid >> 6;
    int g = blockIdx.x * 8 + w;
    if (g >= 6250) return;

    int col = lane & 15, rq = lane >> 4;
    long rowA = (long)g * 16 + col;
    int kg = rq * 8;
    const float* src = mem + rowA * 128;        // L2-hot from phase 1

    short8v ah[4], al[4];
    #pragma unroll
    for (int c = 0; c < 4; ++c) {
        int ko = c * 32 + kg;
        float4 x0 = *(const float4*)&src[ko];
        float4 x1 = *(const float4*)&src[ko + 4];
        split8(x0, x1, ah[c], al[c]);
    }

    #pragma unroll
    for (int t = 0; t < 8; ++t) {
        float b0 = b_tsq[t * 16 + col];
        f32x4 a; a[0] = b0; a[1] = b0; a[2] = b0; a[3] = b0;
        #pragma unroll
        for (int c = 0; c < 4; ++c) {
            int off = ((t * 4 + c) * 64 + lane) * 8;
            short8v bh = *(const short8v*)&Bh[off];
            short8v bl = *(const short8v*)&Bl[off];
            a = __builtin_amdgcn_mfma_f32_16x16x32_bf16(al[c], bh, a, 0, 0, 0);
            a = __builtin_amdgcn_mfma_f32_16x16x32_bf16(ah[c], bl, a, 0, 0, 0);
            a = __builtin_amdgcn_mfma_f32_16x16x32_bf16(ah[c], bh, a, 0, 0, 0);
        }
        #pragma unroll
        for (int r = 0; r < 4; ++r)
            proj[((long)g * 16 + rq * 4 + r) * 128 + t * 16 + col] = a[r];
    }
}

// ---------------------------------------------------------------- k_ht_mfma
__global__ __launch_bounds__(512, 2) void k_ht_mfma(float* __restrict__ ws)
{
    __shared__ short Bh[16384], Bl[16384];
    const short* frh = (const short*)(ws + FR_T_HI);
    const short* frl = (const short*)(ws + FR_T_LO);
    int tid = threadIdx.x;
    for (int i2 = tid; i2 < 2048; i2 += 512) {
        ((uint4*)Bh)[i2] = ((const uint4*)frh)[i2];
        ((uint4*)Bl)[i2] = ((const uint4*)frl)[i2];
    }
    __syncthreads();

    const float* mtv = ws + WS_MTV;
    const float* mtq = ws + WS_MTQ;
    const float* bc  = ws + BC_T;
    float* ht = ws + WS_HT;

    int lane = tid & 63, w = tid >> 6;
    int col = lane & 15, rq = lane >> 4;
    int g = blockIdx.x * 8 + w;
    int p = g * 16 + col;
    int i = p >> 7, j = p & 127;
    int kg = rq * 8;
    const float* vj = mtv + j * 128;
    const float* qi = mtq + i * 128;

    short8v ah[4], al[4];
    #pragma unroll
    for (int c = 0; c < 4; ++c) {
        int ko = c * 32 + kg;
        float4 v0 = *(const float4*)&vj[ko], v1 = *(const float4*)&vj[ko + 4];
        float4 q0 = *(const float4*)&qi[ko], q1 = *(const float4*)&qi[ko + 4];
        float4 r0 = make_float4(fmaxf(v0.x - q0.x, 0.f), fmaxf(v0.y - q0.y, 0.f),
                                fmaxf(v0.z - q0.z, 0.f), fmaxf(v0.w - q0.w, 0.f));
        float4 r1 = make_float4(fmaxf(v1.x - q1.x, 0.f), fmaxf(v1.y - q1.y, 0.f),
                                fmaxf(v1.z - q1.z, 0.f), fmaxf(v1.w - q1.w, 0.f));
        split8(r0, r1, ah[c], al[c]);
    }

    f32x4 acc[8];
    #pragma unroll
    for (int t = 0; t < 8; ++t) {
        float b0 = bc[t * 16 + col];
        f32x4 a; a[0] = b0; a[1] = b0; a[2] = b0; a[3] = b0;
        #pragma unroll
        for (int c = 0; c < 4; ++c) {
            int off = ((t * 4 + c) * 64 + lane) * 8;
            short8v bh = *(const short8v*)&Bh[off];
            short8v bl = *(const short8v*)&Bl[off];
            a = __builtin_amdgcn_mfma_f32_16x16x32_bf16(al[c], bh, a, 0, 0, 0);
            a = __builtin_amdgcn_mfma_f32_16x16x32_bf16(ah[c], bl, a, 0, 0, 0);
            a = __builtin_amdgcn_mfma_f32_16x16x32_bf16(ah[c], bh, a, 0, 0, 0);
        }
        acc[t] = a;
    }

    #pragma unroll
    for (int r = 0; r < 4; ++r) {
        long rho = g * 16 + rq * 4 + r;
        float s_uu = 0.f;
        #pragma unroll
        for (int t = 0; t < 8; ++t) { float u = acc[t][r]; s_uu = fmaf(u, u, s_uu); }
        #pragma unroll
        for (int m = 1; m < 16; m <<= 1) s_uu += __shfl_xor(s_uu, m);
        float rn = rsqrtf(s_uu);
        #pragma unroll
        for (int t = 0; t < 8; ++t)
            ht[rho * 128 + t * 16 + col] = acc[t][r] * rn;
    }
}

// ---------------------------------------------------------------- k_neg_mfma
// EXACT round-2 structure: 278528 rows = 17408 groups of 16, ONE group per
// wave, grid 2176 x 512. (VGPR 52, 55.5us measured.)
__global__ __launch_bounds__(512, 2) void k_neg_mfma(
    const float* __restrict__ ws, const int* __restrict__ idx,
    const float* __restrict__ proj, float* __restrict__ out)
{
    __shared__ short Bh[16384], Bl[16384];
    const short* frh = (const short*)(ws + FR_TS_HI);
    const short* frl = (const short*)(ws + FR_TS_LO);
    int tid = threadIdx.x;
    for (int i2 = tid; i2 < 2048; i2 += 512) {
        ((uint4*)Bh)[i2] = ((const uint4*)frh)[i2];
        ((uint4*)Bl)[i2] = ((const uint4*)frl)[i2];
    }
    __syncthreads();

    const float* msv  = ws + WS_MSV;
    const float* mspq = ws + WS_MSPQ;
    const float* ht   = ws + WS_HT;
    const float* bc   = ws + BC_TS;

    int lane = tid & 63, w = tid >> 6;
    int col = lane & 15, rq = lane >> 4;
    int g = blockIdx.x * 8 + w;

    int rowA = g * 16 + col;
    int p = rowA / 17;
    int slot = rowA - p * 17;
    const float* src = slot ? (proj + (long)idx[p * 17 + slot - 1] * 128)
                            : (mspq + (p >> 7) * 128);
    const float* vj = msv + (p & 127) * 128;
    int kg = rq * 8;

    short8v ah[4], al[4];
    #pragma unroll
    for (int c = 0; c < 4; ++c) {
        int ko = c * 32 + kg;
        float4 v0 = *(const float4*)&vj[ko],  v1 = *(const float4*)&vj[ko + 4];
        float4 q0 = *(const float4*)&src[ko], q1 = *(const float4*)&src[ko + 4];
        float4 r0 = make_float4(fmaxf(v0.x - q0.x, 0.f), fmaxf(v0.y - q0.y, 0.f),
                                fmaxf(v0.z - q0.z, 0.f), fmaxf(v0.w - q0.w, 0.f));
        float4 r1 = make_float4(fmaxf(v1.x - q1.x, 0.f), fmaxf(v1.y - q1.y, 0.f),
                                fmaxf(v1.z - q1.z, 0.f), fmaxf(v1.w - q1.w, 0.f));
        split8(r0, r1, ah[c], al[c]);
    }

    f32x4 acc[8];
    #pragma unroll
    for (int t = 0; t < 8; ++t) {
        float b0 = bc[t * 16 + col];
        f32x4 a; a[0] = b0; a[1] = b0; a[2] = b0; a[3] = b0;
        #pragma unroll
        for (int c = 0; c < 4; ++c) {
            int off = ((t * 4 + c) * 64 + lane) * 8;
            short8v bh = *(const short8v*)&Bh[off];
            short8v bl = *(const short8v*)&Bl[off];
            a = __builtin_amdgcn_mfma_f32_16x16x32_bf16(al[c], bh, a, 0, 0, 0);
            a = __builtin_amdgcn_mfma_f32_16x16x32_bf16(ah[c], bl, a, 0, 0, 0);
            a = __builtin_amdgcn_mfma_f32_16x16x32_bf16(ah[c], bh, a, 0, 0, 0);
        }
        acc[t] = a;
    }

    #pragma unroll
    for (int r = 0; r < 4; ++r) {
        int rho = g * 16 + rq * 4 + r;
        int pe = rho / 17;
        const float* hrow = ht + (long)pe * 128 + col;
        float s_uu = 0.f, s_hu = 0.f;
        #pragma unroll
        for (int t = 0; t < 8; ++t) {
            float u = acc[t][r];
            s_uu = fmaf(u, u, s_uu);
            s_hu = fmaf(hrow[t * 16], u, s_hu);
        }
        #pragma unroll
        for (int m = 1; m < 16; m <<= 1) {
            s_uu += __shfl_xor(s_uu, m);
            s_hu += __shfl_xor(s_hu, m);
        }
        if (col == 0)
            out[rho] = __expf((s_hu * rsqrtf(s_uu) - 1.0f) * INV_T);
    }
}

// ---------------------------------------------------------------- k_memupd
__global__ __launch_bounds__(128) void k_memupd(
    const float* __restrict__ mem, const float* __restrict__ se,
    const int* __restrict__ y, float* __restrict__ dst)
{
    int b = blockIdx.x;
    int d = threadIdx.x;
    int yb = y[b];
    for (int b2 = b + 1; b2 < BB; ++b2)
        if (y[b2] == yb) return;

    float ab = 0.5f * mem[(long)yb * 128 + d] + 0.5f * se[b * 128 + d];
    float ss = ab * ab;
    #pragma unroll
    for (int mq = 32; mq; mq >>= 1) ss += __shfl_xor(ss, mq);
    __shared__ float partial[2];
    if ((d & 63) == 0) partial[d >> 6] = ss;
    __syncthreads();
    float tot = partial[0] + partial[1];
    dst[(long)yb * 128 + d] = ab * rsqrtf(tot);
}

// ---------------------------------------------------------------- launch
extern "C" void kernel_launch(void* const* d_in, const int* in_sizes, int n_in,
                              void* d_out, int out_size, void* d_ws, size_t ws_size,
                              hipStream_t stream)
{
    const float* s     = (const float*)d_in[0];
    const float* t     = (const float*)d_in[1];
    const int*   y     = (const int*)  d_in[2];
    const int*   idx   = (const int*)  d_in[3];
    const float* mem   = (const float*)d_in[4];
    const float* W_es  = (const float*)d_in[5];  const float* b_es  = (const float*)d_in[6];
    const float* W_et  = (const float*)d_in[7];  const float* b_et  = (const float*)d_in[8];
    const float* W_tv  = (const float*)d_in[9];  const float* b_tv  = (const float*)d_in[10];
    const float* W_tq  = (const float*)d_in[11]; const float* b_tq  = (const float*)d_in[12];
    const float* W_tsv = (const float*)d_in[13]; const float* b_tsv = (const float*)d_in[14];
    const float* W_tsq = (const float*)d_in[15]; const float* b_tsq = (const float*)d_in[16];
    const float* W_mt  = (const float*)d_in[17]; const float* b_mt  = (const float*)d_in[18];
    const float* W_mts = (const float*)d_in[19]; const float* b_mts = (const float*)d_in[20];
    const float* W_ht  = (const float*)d_in[21]; const float* b_ht  = (const float*)d_in[22];
    const float* W_hts = (const float*)d_in[23]; const float* b_hts = (const float*)d_in[24];

    float* out  = (float*)d_out;
    float* ws   = (float*)d_ws;
    float* proj = ws + WS_PROJ;

    k_compose <<<16, 256, 0, stream>>>(W_mts, b_mts, W_hts, b_hts,
                                       W_mt, b_mt, W_ht, b_ht, ws);
    k_embed   <<<256, 128, 0, stream>>>(s, t, W_es, b_es, W_et, b_et, ws);
    k_projcopy<<<782, 512, 0, stream>>>(mem, b_tsq, W_tsq, proj, out + OUT_MEM);
    k_proj4   <<<512, 128, 0, stream>>>(W_tv, b_tv, W_tq, b_tq, W_tsv, b_tsv, W_tsq, b_tsq, ws);
    k_ht_mfma <<<128, 512, 0, stream>>>(ws);
    k_neg_mfma<<<2176, 512, 0, stream>>>(ws, idx, proj, out);
    k_memupd  <<<128, 128, 0, stream>>>(mem, ws + WS_SE, y, out + OUT_MEM);
}